// Round 6
// baseline (122.231 us; speedup 1.0000x reference)
//
#include <hip/hip_runtime.h>
#include <math.h>

// B=2, N=512, DIM=512, HEADS=8, DIM_HEAD=64
// out[be,mu,z] = FFT1024(S_k*v)[mu] / FFT1024(k_)[mu],  mu in [0,512)
// after a 2x8 (b,h)-DFT; inputs zero-padded 512 -> 1024 on the m axis.
// Gk/Gp layout: [be][m][z] (z fastest).

#define DIMX 512
#define NPOS 512
#define PADIDX(m) ((m) + ((m) >> 4))

// ---------------- GEMM v4: x-only LDS, W streamed from global/L1 ------------
// 32x128 tiles, grid 256 (1 block/CU). Thread (tc 0..31, tr 0..7) = 4x4 acc.
// Per 4-kk chunk/wave: 4 ds_read_b128 (x, 2-way broadcast = free) = ~48 LDS
// cyc vs 128 FMA-issue cyc; W comes via VMEM (parallel pipe, L1-cached,
// prefetched one chunk ahead). LDS pipe no longer the wall.
__global__ __launch_bounds__(256)
void gemm_kv_kernel(const float* __restrict__ x,
                    const float* __restrict__ Wk,
                    const float* __restrict__ Wv,
                    float* __restrict__ K,
                    float* __restrict__ V,
                    float* __restrict__ partials)
{
    const int blk  = blockIdx.x;          // 0..255
    const int sel  = blk >> 7;            // 0 -> K, 1 -> V
    const int tid  = blk & 127;
    const int row0 = (tid >> 2) * 32;     // 32 row-tiles
    const int col0 = (tid & 3) * 128;     // 4 col-tiles
    const int t    = threadIdx.x;
    const int tc   = t & 31;
    const int tr   = t >> 5;              // 0..7
    const float* __restrict__ W   = sel ? Wv : Wk;
    float* __restrict__       Out = sel ? V  : K;

    __shared__ float xs[32][DIMX];        // 64 KB, staged once
    __shared__ float red[4];

    for (int e = t * 4; e < 32 * DIMX; e += 1024) {
        const int row = e >> 9, k = e & 511;
        *(float4*)&xs[row][k] = *(const float4*)&x[(size_t)(row0 + row) * DIMX + k];
    }
    __syncthreads();

    float acc[4][4] = {{0,0,0,0},{0,0,0,0},{0,0,0,0},{0,0,0,0}};
    const float* Wb = W + col0 + tc * 4;  // column base for this thread

    float4 wnext[4];
    #pragma unroll
    for (int j = 0; j < 4; ++j)
        wnext[j] = *(const float4*)&Wb[(size_t)j * DIMX];

    for (int kb = 0; kb < 128; ++kb) {
        float4 wcur[4];
        #pragma unroll
        for (int j = 0; j < 4; ++j) wcur[j] = wnext[j];
        if (kb < 127) {
            #pragma unroll
            for (int j = 0; j < 4; ++j)
                wnext[j] = *(const float4*)&Wb[(size_t)((kb + 1) * 4 + j) * DIMX];
        }
        float4 xv[4];
        #pragma unroll
        for (int i = 0; i < 4; ++i)
            xv[i] = *(const float4*)&xs[tr * 4 + i][kb * 4];
        #pragma unroll
        for (int i = 0; i < 4; ++i) {
            #pragma unroll
            for (int cc = 0; cc < 4; ++cc) {
                float a = (&acc[i][0])[cc];
                a = fmaf(xv[i].x, (&wcur[0].x)[cc], a);
                a = fmaf(xv[i].y, (&wcur[1].x)[cc], a);
                a = fmaf(xv[i].z, (&wcur[2].x)[cc], a);
                a = fmaf(xv[i].w, (&wcur[3].x)[cc], a);
                (&acc[i][0])[cc] = a;
            }
        }
    }

    float ss = 0.f;
    #pragma unroll
    for (int i = 0; i < 4; ++i) {
        const int row = row0 + tr * 4 + i;
        const float4 o = make_float4(acc[i][0], acc[i][1], acc[i][2], acc[i][3]);
        *(float4*)&Out[(size_t)row * DIMX + col0 + tc * 4] = o;
        ss += o.x * o.x + o.y * o.y + o.z * o.z + o.w * o.w;
    }
    if (sel == 0) {   // Frobenius sumsq of K -> per-block partial
        #pragma unroll
        for (int off = 32; off > 0; off >>= 1)
            ss += __shfl_down(ss, off, 64);
        if ((t & 63) == 0) red[t >> 6] = ss;
        __syncthreads();
        if (t == 0) partials[blk] = red[0] + red[1] + red[2] + red[3];
    } else {
        if (t == 0) partials[blk] = 0.f;
    }
}

// 8-point DFT twiddles: exp(-2*pi*i*k/8)
__device__ __constant__ float C8[8] = {
    1.f, 0.70710678118654752440f, 0.f, -0.70710678118654752440f,
   -1.f, -0.70710678118654752440f, 0.f, 0.70710678118654752440f };
__device__ __constant__ float S8[8] = {
    0.f, -0.70710678118654752440f, -1.f, -0.70710678118654752440f,
    0.f,  0.70710678118654752440f,  1.f,  0.70710678118654752440f };

// elu(K/norm), S_k, P = S_k*V, 2x8 (b,h)-DFT. Writes [be][m][z], float4.
__global__ __launch_bounds__(256)
void stage1_kernel(const float* __restrict__ K,
                   const float* __restrict__ V,
                   const float* __restrict__ partials,
                   float2* __restrict__ Gk,
                   float2* __restrict__ Gp)
{
    const int m = blockIdx.x;     // 0..511
    const int t = threadIdx.x;
    __shared__ float kk[2][8][64];
    __shared__ float pp[2][8][64];
    __shared__ float skp[16][4];
    __shared__ float sk[2][8];
    __shared__ float sred[4];

    // reduce the 256 gemm partials -> global Frobenius scale
    float p = partials[t];
    #pragma unroll
    for (int off = 32; off > 0; off >>= 1)
        p += __shfl_down(p, off, 64);
    if ((t & 63) == 0) sred[t >> 6] = p;
    __syncthreads();
    const float scale = (float)(1.0 / sqrt((double)sred[0] + (double)sred[1] +
                                           (double)sred[2] + (double)sred[3]));

    for (int e = t; e < 1024; e += 256) {
        const int b = e >> 9, rem = e & 511, h = rem >> 6, z = rem & 63;
        const size_t src = (size_t)(b * 512 + m) * DIMX + h * 64 + z;
        const float kv = K[src] * scale;
        kk[b][h][z] = kv > 0.f ? kv : expm1f(kv);
        pp[b][h][z] = V[src];
    }
    __syncthreads();
    if (t < 64) {               // sk[b][h] = sum_z elu(k): 4 threads per (b,h)
        const int bh = t >> 2, q = t & 3;
        float s = 0.f;
        #pragma unroll
        for (int zz = 0; zz < 16; ++zz) s += kk[bh >> 3][bh & 7][q * 16 + zz];
        skp[bh][q] = s;
    }
    __syncthreads();
    if (t < 16) sk[t >> 3][t & 7] = skp[t][0] + skp[t][1] + skp[t][2] + skp[t][3];
    __syncthreads();
    for (int e = t; e < 1024; e += 256) {
        const int b = e >> 9, rem = e & 511, h = rem >> 6, z = rem & 63;
        pp[b][h][z] *= sk[b][h];
    }
    __syncthreads();

    // 2x8 (b,h)-DFT; each thread computes a z-PAIR -> float4 stores.
    for (int e2 = t; e2 < 512; e2 += 256) {
        const int be = e2 >> 5;          // 0..15
        const int zp = e2 & 31;          // z pair index
        const int beta = be >> 3, eta = be & 7;
        float4 rk, rp;
        #pragma unroll
        for (int zz = 0; zz < 2; ++zz) {
            const int z = zp * 2 + zz;
            float gkr = 0.f, gki = 0.f, gpr = 0.f, gpi = 0.f;
            #pragma unroll
            for (int b = 0; b < 2; ++b) {
                const float sgn = (beta & b) ? -1.f : 1.f;
                #pragma unroll
                for (int h = 0; h < 8; ++h) {
                    const int ph = (eta * h) & 7;
                    const float cr = C8[ph], ci = S8[ph];
                    const float a = kk[b][h][z] * sgn;
                    gkr = fmaf(a, cr, gkr); gki = fmaf(a, ci, gki);
                    const float p2 = pp[b][h][z] * sgn;
                    gpr = fmaf(p2, cr, gpr); gpi = fmaf(p2, ci, gpi);
                }
            }
            if (zz == 0) { rk.x = gkr; rk.y = gki; rp.x = gpr; rp.y = gpi; }
            else         { rk.z = gkr; rk.w = gki; rp.z = gpr; rp.w = gpi; }
        }
        const size_t o = ((size_t)be * NPOS + m) * 64 + zp * 2;
        *(float4*)&Gk[o] = rk;
        *(float4*)&Gp[o] = rp;
    }
}

// ---------------- Zero-padded 1024-pt radix-2 DIF FFT + divide ----------------
// Swizzle: blk = be*32 + l*8 + j, zg = j*4 + l  ->  the 4 blocks sharing each
// 64B out-line / Gk-line (zg group of 4, fixed be) have equal blk%8 (same XCD).
__global__ __launch_bounds__(256)
void fft_div_kernel(const float2* __restrict__ Gk,   // [be][m][z]
                    const float2* __restrict__ Gp,
                    float* __restrict__ out, int out_cplx)
{
    const int blk = blockIdx.x;
    const int j  = blk & 7;
    const int l  = (blk >> 3) & 3;
    const int be = blk >> 5;
    const int zg = j * 4 + l;            // z = 2*zg, 2*zg+1
    const int t  = threadIdx.x;

    __shared__ float2 g[4][1088];   // arr = a*2+zi, padded 1024 -> 1088
    __shared__ float2 w[544];       // padded 512 twiddles

    for (int jj = t; jj < 512; jj += 256) {
        double s, cc;
        sincos(-6.2831853071795864769 * (double)jj / 1024.0, &s, &cc);
        w[PADIDX(jj)] = make_float2((float)cc, (float)s);
    }
    __syncthreads();

    // load z-pair as float4 + fused stage 0 (upper half of input is zero)
    for (int e = t; e < 1024; e += 256) {
        const int a = e >> 9;            // 0 -> Gk, 1 -> Gp
        const int m = e & 511;
        const float4 v4 = *(const float4*)&(a ? Gp : Gk)[((size_t)be * NPOS + m) * 64 + zg * 2];
        const float2 v0 = make_float2(v4.x, v4.y);
        const float2 v1 = make_float2(v4.z, v4.w);
        const float2 tw = w[PADIDX(m)];
        g[a * 2 + 0][PADIDX(m)] = v0;
        g[a * 2 + 1][PADIDX(m)] = v1;
        g[a * 2 + 0][PADIDX(m + 512)] = make_float2(v0.x * tw.x - v0.y * tw.y,
                                                    v0.x * tw.y + v0.y * tw.x);
        g[a * 2 + 1][PADIDX(m + 512)] = make_float2(v1.x * tw.x - v1.y * tw.y,
                                                    v1.x * tw.y + v1.y * tw.x);
    }
    __syncthreads();

    #pragma unroll
    for (int s = 1; s <= 9; ++s) {
        const int S = 512 >> s;
        const int lg = 9 - s;
        #pragma unroll
        for (int q = 0; q < 8; ++q) {
            const int B    = t + 256 * q;
            const int arr  = B >> 9;
            const int beta = B & 511;
            const int jb   = beta & (S - 1);
            const int seg  = beta >> lg;
            const int u    = (seg << (lg + 1)) + jb;
            const int v    = u + S;
            const float2 tw = w[PADIDX(jb << s)];
            const float2 A  = g[arr][PADIDX(u)];
            const float2 Bb = g[arr][PADIDX(v)];
            g[arr][PADIDX(u)] = make_float2(A.x + Bb.x, A.y + Bb.y);
            const float sr = A.x - Bb.x, si = A.y - Bb.y;
            g[arr][PADIDX(v)] = make_float2(sr * tw.x - si * tw.y,
                                            sr * tw.y + si * tw.x);
        }
        __syncthreads();
    }

    // even positions 2i hold mu = bitrev9(i). Divide both z and store float4.
    for (int e2 = t; e2 < 512; e2 += 256) {
        const int i  = e2;
        const int pi = PADIDX(2 * i);
        const int mu = (int)(__brev((unsigned)i) >> 23);   // bitrev9
        float4 res;
        #pragma unroll
        for (int zi = 0; zi < 2; ++zi) {
            const float2 D  = g[zi][pi];
            const float2 Nm = g[2 + zi][pi];
            const float inv = 1.f / (D.x * D.x + D.y * D.y);
            const float rr = (Nm.x * D.x + Nm.y * D.y) * inv;
            const float ri = (Nm.y * D.x - Nm.x * D.y) * inv;
            if (zi == 0) { res.x = rr; res.y = ri; }
            else         { res.z = rr; res.w = ri; }
        }
        const size_t o = ((size_t)be * NPOS + mu) * 64 + zg * 2;
        if (out_cplx) {
            *(float4*)&((float2*)out)[o] = res;
        } else {
            out[o]     = res.x;
            out[o + 1] = res.z;
        }
    }
}

// Fallback mdft (fp64, [be][m][z] layout) for the ws-aliasing path.
__global__ __launch_bounds__(256)
void mdft_fallback_kernel(const float2* __restrict__ Gk,
                          const float2* __restrict__ Gp,
                          float* __restrict__ out,
                          int out_cplx)
{
    const int blk = blockIdx.x;
    const int be = blk >> 6, z = blk & 63;
    const int t = threadIdx.x;
    __shared__ float2 gk[512];
    __shared__ float2 gp[512];
    __shared__ float2 w[1024];

    for (int m = t; m < 512; m += 256) {
        const size_t idx = ((size_t)be * NPOS + m) * 64 + z;
        gk[m] = Gk[idx];
        gp[m] = Gp[idx];
    }
    for (int jj = t; jj < 1024; jj += 256) {
        double s, c;
        sincos(-6.2831853071795864769 * (double)jj / 1024.0, &s, &c);
        w[jj] = make_float2((float)c, (float)s);
    }
    __syncthreads();

    #pragma unroll
    for (int half = 0; half < 2; ++half) {
        const int mu = t + half * 256;
        double dr = 0.0, di = 0.0, nr = 0.0, ni = 0.0;
        int idx = 0;
        for (int m = 0; m < 512; ++m) {
            const float2 tw = w[idx];
            idx = (idx + mu) & 1023;
            const float2 a = gk[m];
            dr += (double)(a.x * tw.x - a.y * tw.y);
            di += (double)(a.x * tw.y + a.y * tw.x);
            const float2 p = gp[m];
            nr += (double)(p.x * tw.x - p.y * tw.y);
            ni += (double)(p.x * tw.y + p.y * tw.x);
        }
        const double dmag = dr * dr + di * di;
        const double orr = (nr * dr + ni * di) / dmag;
        const double oii = (ni * dr - nr * di) / dmag;
        const size_t o = ((size_t)be * NPOS + mu) * 64 + z;
        if (out_cplx) {
            out[2 * o]     = (float)orr;
            out[2 * o + 1] = (float)oii;
        } else {
            out[o] = (float)orr;
        }
    }
}

extern "C" void kernel_launch(void* const* d_in, const int* in_sizes, int n_in,
                              void* d_out, int out_size, void* d_ws, size_t ws_size,
                              hipStream_t stream)
{
    // inputs: x, Wq, Wk, Wv, Er — only x, Wk, Wv needed
    const float* x  = (const float*)d_in[0];
    const float* Wk = (const float*)d_in[2];
    const float* Wv = (const float*)d_in[3];
    float* out = (float*)d_out;

    char* ws = (char*)d_ws;
    float*  K    = (float*)(ws);                           // 2 MB
    float*  V    = (float*)(ws + (size_t)2097152);         // 2 MB
    float2* Gk   = (float2*)(ws + (size_t)4194304);        // 4 MB
    float*  part = (float*)(ws + (size_t)8388608);         // 1 KB (256 floats)
    const int out_cplx = (out_size >= 2 * 2 * 8 * 512 * 64) ? 1 : 0;

    const bool ws_big = (ws_size >= (size_t)8390656 + (size_t)4194304);
    float2* Gp = ws_big ? (float2*)(ws + (size_t)8390656)  // 4 MB
                        : (float2*)d_out;                  // alias-safe fallback

    hipLaunchKernelGGL(gemm_kv_kernel, dim3(256), dim3(256), 0, stream,
                       x, Wk, Wv, K, V, part);
    hipLaunchKernelGGL(stage1_kernel, dim3(512), dim3(256), 0, stream,
                       K, V, part, Gk, Gp);
    if (ws_big) {
        hipLaunchKernelGGL(fft_div_kernel, dim3(512), dim3(256), 0, stream,
                           Gk, Gp, out, out_cplx);
    } else {
        hipLaunchKernelGGL(mdft_fallback_kernel, dim3(1024), dim3(256), 0, stream,
                           Gk, Gp, out, out_cplx);
    }
}